// Round 7
// baseline (155.761 us; speedup 1.0000x reference)
//
#include <hip/hip_runtime.h>
#include <hip/hip_bf16.h>
#include <stdint.h>

#define PDIM 4096
#define KSEL 3687.0f
#define NITER 50

typedef unsigned short ushort_t;
typedef __attribute__((ext_vector_type(8))) __bf16 bf16x8;
typedef __attribute__((ext_vector_type(4))) float f32x4;

typedef __attribute__((address_space(3))) void lds_void;
typedef __attribute__((address_space(1))) const void glob_void;

__device__ __forceinline__ ushort_t f32_to_bf16_rne(float f) {
  union { float f; uint32_t u; } v; v.f = f;
  uint32_t r = 0x7FFFu + ((v.u >> 16) & 1u);
  return (ushort_t)((v.u + r) >> 16);
}

__device__ __forceinline__ float bf16_to_f32(ushort_t h) {
  union { uint32_t u; float f; } v; v.u = ((uint32_t)h) << 16;
  return v.f;
}

__device__ __forceinline__ void async_cp16(const void* g, void* l) {
  __builtin_amdgcn_global_load_lds((glob_void*)g, (lds_void*)l, 16, 0, 0);
}

// Raw workgroup barrier with compiler fences (rule #18).
__device__ __forceinline__ void raw_barrier() {
  __builtin_amdgcn_sched_barrier(0);
  asm volatile("" ::: "memory");
  __builtin_amdgcn_s_barrier();
  asm volatile("" ::: "memory");
  __builtin_amdgcn_sched_barrier(0);
}

// Canonical CDNA wave64 sum via DPP; result lands in lane 63.
__device__ __forceinline__ float wave_sum_dpp(float x) {
  float s = x;
  int t;
  t = __builtin_amdgcn_update_dpp(0, __float_as_int(s), 0x111, 0xF, 0xF, true);
  s += __int_as_float(t);  // row_shr:1
  t = __builtin_amdgcn_update_dpp(0, __float_as_int(s), 0x112, 0xF, 0xF, true);
  s += __int_as_float(t);  // row_shr:2
  t = __builtin_amdgcn_update_dpp(0, __float_as_int(s), 0x114, 0xF, 0xF, true);
  s += __int_as_float(t);  // row_shr:4
  t = __builtin_amdgcn_update_dpp(0, __float_as_int(s), 0x118, 0xF, 0xF, true);
  s += __int_as_float(t);  // row_shr:8
  t = __builtin_amdgcn_update_dpp(0, __float_as_int(s), 0x142, 0xA, 0xF, true);
  s += __int_as_float(t);  // row_bcast:15
  t = __builtin_amdgcn_update_dpp(0, __float_as_int(s), 0x143, 0xC, 0xF, true);
  s += __int_as_float(t);  // row_bcast:31 -> lane63 = all 64
  return s;
}

// ---------------- Kernel 1: fused Dykstra (block 0) + V->LLC prefetch
// (blocks 1..2048) + x->bf16 (blocks 2049..). R3-proven.
__global__ __launch_bounds__(256) void prep_kernel(
    const float* __restrict__ alpha, float* __restrict__ a_out,
    const float* __restrict__ x, ushort_t* __restrict__ Xb, int n4,
    const float* __restrict__ V) {
  if (blockIdx.x >= 1 && blockIdx.x <= 2048) {
    const float4* V4 = (const float4*)V;
    const int base = (blockIdx.x - 1) * 2048 + (int)threadIdx.x;
#pragma unroll
    for (int i = 0; i < 8; ++i) {
      const float4 vv = V4[base + i * 256];
      asm volatile("" :: "v"(vv.x), "v"(vv.y), "v"(vv.z), "v"(vv.w));
    }
    return;
  }
  if (blockIdx.x != 0) {
    const int i = (blockIdx.x - 2049) * 256 + threadIdx.x;
    if (i < n4) {
      const float4 v = ((const float4*)x)[i];
      ushort4 o;
      o.x = f32_to_bf16_rne(v.x);
      o.y = f32_to_bf16_rne(v.y);
      o.z = f32_to_bf16_rne(v.z);
      o.w = f32_to_bf16_rne(v.w);
      ((ushort4*)Xb)[i] = o;
    }
    return;
  }
  __shared__ float red[8];
  const int tid = threadIdx.x;
  const int lane = tid & 63;
  const int wv = tid >> 6;
  float xx[16], q[16];
  float p = 0.0f;
#pragma unroll
  for (int i = 0; i < 16; ++i) {
    xx[i] = alpha[i * 256 + tid] * 100.0f;  // s = alpha / 0.01
    q[i] = 0.0f;
  }
  for (int it = 0; it < NITER; ++it) {
    float t[16];
    float loc = 0.0f;
#pragma unroll
    for (int i = 0; i < 16; ++i) { t[i] = xx[i] + p; loc += t[i]; }
    loc = wave_sum_dpp(loc);
    const int slot = (it & 1) * 4;
    if (lane == 63) red[slot + wv] = loc;
    __syncthreads();
    const float tot = red[slot] + red[slot + 1] + red[slot + 2] + red[slot + 3];
    const float corr = (KSEL - tot) * (1.0f / 4096.0f);
    p = -corr;
#pragma unroll
    for (int i = 0; i < 16; ++i) {
      const float y = t[i] + corr;
      const float u = y + q[i];
      const float xn = fminf(fmaxf(u, 0.0f), 1.0f);
      q[i] = u - xn;
      xx[i] = xn;
    }
  }
#pragma unroll
  for (int i = 0; i < 16; ++i) a_out[i * 256 + tid] = xx[i];
}

// ---------------- Kernel 2: materialize W (row-major bf16) ----------------
// 128x64 tile, 192-row fp32 V band in LDS, pad 67. V reads LLC-hit. R3.
__global__ __launch_bounds__(256) void wmat_kernel(
    const float* __restrict__ V, const float* __restrict__ a,
    ushort_t* __restrict__ Wb) {
  __shared__ float vt[192][67];
  const int t = threadIdx.x;
  const int r0 = blockIdx.x * 128;
  const int c0 = blockIdx.y * 64;
  const int dbase = (r0 - c0 - 63 + 2 * PDIM) & (PDIM - 1);
  const int csub = (t & 15) * 4;
  const int rsub = t >> 4;
#pragma unroll
  for (int i = 0; i < 12; ++i) {
    const int ld = i * 16 + rsub;
    const int d = (dbase + ld) & (PDIM - 1);
    const float av = a[d];
    const float4 vv = *(const float4*)(V + (size_t)d * PDIM + c0 + csub);
    vt[ld][csub + 0] = av * vv.x;
    vt[ld][csub + 1] = av * vv.y;
    vt[ld][csub + 2] = av * vv.z;
    vt[ld][csub + 3] = av * vv.w;
  }
  __syncthreads();
#pragma unroll
  for (int k = 0; k < 4; ++k) {
    const int ry = (t >> 3) + k * 32;
    const int cb = (t & 7) * 8;
    ushort_t pk[8];
#pragma unroll
    for (int j = 0; j < 8; ++j) {
      const int c = cb + j;
      pk[j] = f32_to_bf16_rne(vt[ry - c + 63][c]);
    }
    *(uint4*)(Wb + (size_t)(r0 + ry) * PDIM + c0 + cb) = *(const uint4*)pk;
  }
}

// ---------------- Kernel 3: bf16 MFMA GEMM, BM=BN=256, BK=64, z=8 --------
// R7: 8-phase schedule on R6's proven geometry. Per K-tile, 4 phases:
// {stage 1 half-tile of t+1 || ds_read one m-pair quadrant} -> barrier ->
// lgkmcnt(0) -> setprio(1) -> 16 MFMA -> setprio(0) -> barrier.
// vmcnt(0) only at q=3 (once per K-tile); t+1's loads get ~3 phases of
// MFMA latency cover. Staging always targets the non-read buffer; the
// q=3 vmcnt+barrier orders both buffer-reuse edges.
__global__ __launch_bounds__(512, 2) void gemm_kernel(
    const ushort_t* __restrict__ Xb, const ushort_t* __restrict__ Wb,
    ushort_t* __restrict__ par) {
  constexpr int Kdim = 4096, KQ = 512, NIT = KQ / 64;
  __shared__ __align__(16) ushort_t As[2][256 * 64];
  __shared__ __align__(16) ushort_t Bs[2][256 * 64];
  const int tid = threadIdx.x;
  const int lane = tid & 63;
  const int w = tid >> 6;        // 0..7
  const int l15 = lane & 15;
  const int quad = lane >> 4;
  const int wr = w >> 2;         // 0..1 (M half)
  const int wc = w & 3;          // 0..3 (N quarter)
  // XCD decode: bid%8 = XCD (round-robin); each XCD gets 4 tiles x all z.
  const int bid = blockIdx.x;    // 0..255
  const int u = (bid & 7) * 32 + (bid >> 3);
  const int z = u & 7;
  const int tile = u >> 3;       // 0..31
  const int mblk = tile & 1;
  const int nblk = tile >> 1;    // 0..15
  const int m0 = mblk * 256;
  const int n0 = nblk * 256;
  const int kbase = z * KQ;
  const int crow8 = lane >> 3;   // 0..7
  const int slotj = lane & 7;

  f32x4 acc[8][4];
#pragma unroll
  for (int mt = 0; mt < 8; ++mt)
#pragma unroll
    for (int nt = 0; nt < 4; ++nt) acc[mt][nt] = (f32x4){0.f, 0.f, 0.f, 0.f};

  // Stage half-tile q of K-tile `it` into buffer `buf` (2 cp16/thread).
  // q: 0=A rows 0..127, 1=A rows 128..255, 2=B rows 0..127, 3=B rows 128..255
  auto stage_half = [&](int buf, int it, int q) {
    const int k0 = kbase + it * 64;
    const int half = q & 1;
#pragma unroll
    for (int L = 0; L < 2; ++L) {
      const int chunk = half * 16 + L * 8 + w;   // 0..31
      const int row = chunk * 8 + crow8;         // 0..255
      const int j = slotj ^ (row & 7);
      if (q < 2)
        async_cp16(Xb + (size_t)(m0 + row) * Kdim + k0 + j * 8,
                   (char*)&As[buf][0] + (size_t)chunk * 1024);
      else
        async_cp16(Wb + (size_t)(n0 + row) * Kdim + k0 + j * 8,
                   (char*)&Bs[buf][0] + (size_t)chunk * 1024);
    }
  };

  // Prologue: stage full K-tile 0, drain, sync.
#pragma unroll
  for (int q = 0; q < 4; ++q) stage_half(0, 0, q);
  asm volatile("s_waitcnt vmcnt(0)" ::: "memory");
  raw_barrier();

  for (int t = 0; t < NIT; ++t) {
    const int cur = t & 1;
    const ushort_t* __restrict__ Ab = &As[cur][0];
    const ushort_t* __restrict__ Bb = &Bs[cur][0];
    bf16x8 bfr[4][2];
#pragma unroll
    for (int q = 0; q < 4; ++q) {
      // stage half-tile q of next K-tile into the other buffer
      if (t + 1 < NIT) stage_half(cur ^ 1, t + 1, q);
      // ds_read this phase's fragments from the current buffer
      if (q == 0) {
#pragma unroll
        for (int nt = 0; nt < 4; ++nt)
#pragma unroll
          for (int k2 = 0; k2 < 2; ++k2) {
            const int row = wc * 64 + nt * 16 + l15;
            const int cj = k2 * 4 + quad;
            bfr[nt][k2] =
                *(const bf16x8*)&Bb[(row * 8 + (cj ^ (row & 7))) * 8];
          }
      }
      bf16x8 afr[2][2];
#pragma unroll
      for (int mi = 0; mi < 2; ++mi)
#pragma unroll
        for (int k2 = 0; k2 < 2; ++k2) {
          const int row = wr * 128 + (q * 2 + mi) * 16 + l15;
          const int cj = k2 * 4 + quad;
          afr[mi][k2] = *(const bf16x8*)&Ab[(row * 8 + (cj ^ (row & 7))) * 8];
        }
      raw_barrier();  // phase-lock waves before the MFMA cluster
      asm volatile("s_waitcnt lgkmcnt(0)" ::: "memory");
      __builtin_amdgcn_sched_barrier(0);  // rule #18: pin MFMA below wait
      __builtin_amdgcn_s_setprio(1);
#pragma unroll
      for (int mi = 0; mi < 2; ++mi)
#pragma unroll
        for (int nt = 0; nt < 4; ++nt) {
          acc[q * 2 + mi][nt] = __builtin_amdgcn_mfma_f32_16x16x32_bf16(
              afr[mi][0], bfr[nt][0], acc[q * 2 + mi][nt], 0, 0, 0);
          acc[q * 2 + mi][nt] = __builtin_amdgcn_mfma_f32_16x16x32_bf16(
              afr[mi][1], bfr[nt][1], acc[q * 2 + mi][nt], 0, 0, 0);
        }
      __builtin_amdgcn_s_setprio(0);
      // K-tile boundary: own t+1 loads retired before the barrier so other
      // waves may read them next tile; barrier also closes cur-buf reads
      // before t+2's DMA (issued next tile) can overwrite it.
      if (q == 3) asm volatile("s_waitcnt vmcnt(0)" ::: "memory");
      raw_barrier();
    }
  }
  // epilogue: bf16 partials, blocked order, 8B/lane coalesced. (R6-proven)
  ushort_t* pbase = par + ((size_t)z * 32 + tile) * 65536;
#pragma unroll
  for (int mt = 0; mt < 8; ++mt) {
#pragma unroll
    for (int nt = 0; nt < 4; ++nt) {
      const int slot = mt * 4 + nt;
      ushort4 o;
      o.x = f32_to_bf16_rne(acc[mt][nt][0]);
      o.y = f32_to_bf16_rne(acc[mt][nt][1]);
      o.z = f32_to_bf16_rne(acc[mt][nt][2]);
      o.w = f32_to_bf16_rne(acc[mt][nt][3]);
      *(ushort4*)(pbase + (size_t)(slot * 512 + tid) * 4) = o;
    }
  }
}

// ---------------- Kernel 4: sum 8 blocked bf16 partials -> row-major out --
// Grid = 32 tiles x 4 quarters (128 blocks x 512 thr). R6-proven.
__global__ __launch_bounds__(512) void combine_kernel(
    const ushort_t* __restrict__ par, float* __restrict__ out) {
  const int tile = blockIdx.x >> 2;  // 0..31
  const int qh = blockIdx.x & 3;
  const int mblk = tile & 1;
  const int nblk = tile >> 1;
  const int m0 = mblk * 256;
  const int n0 = nblk * 256;
  const int tid = threadIdx.x;
  const int lane = tid & 63;
  const int w = tid >> 6;
  const int wr = w >> 2;
  const int wc = w & 3;
  const int l15 = lane & 15;
  const int quad = lane >> 4;
#pragma unroll
  for (int ss = 0; ss < 8; ++ss) {
    const int slot = qh * 8 + ss;  // 0..31
    float s0 = 0.f, s1 = 0.f, s2 = 0.f, s3 = 0.f;
#pragma unroll
    for (int z = 0; z < 8; ++z) {
      const ushort4 v = *(const ushort4*)(par +
          ((size_t)z * 32 + tile) * 65536 + (size_t)(slot * 512 + tid) * 4);
      s0 += bf16_to_f32(v.x);
      s1 += bf16_to_f32(v.y);
      s2 += bf16_to_f32(v.z);
      s3 += bf16_to_f32(v.w);
    }
    const int mt = slot >> 2;
    const int nt = slot & 3;
    const int mb = m0 + wr * 128 + mt * 16 + quad * 4;
    const int n = n0 + wc * 64 + nt * 16 + l15;
    out[(size_t)(mb + 0) * PDIM + n] = s0;
    out[(size_t)(mb + 1) * PDIM + n] = s1;
    out[(size_t)(mb + 2) * PDIM + n] = s2;
    out[(size_t)(mb + 3) * PDIM + n] = s3;
  }
}

extern "C" void kernel_launch(void* const* d_in, const int* in_sizes, int n_in,
                              void* d_out, int out_size, void* d_ws,
                              size_t ws_size, hipStream_t stream) {
  const float* x = (const float*)d_in[0];
  const float* V = (const float*)d_in[1];
  const float* alpha = (const float*)d_in[2];
  float* out = (float*)d_out;
  const int M = in_sizes[0] / PDIM;  // 512

  // ws: a(16KB) | Xb bf16 (4MB) | Wb bf16 (32MB) | partials bf16 8x4MB
  float* a_mask = (float*)d_ws;
  ushort_t* Xb = (ushort_t*)((char*)d_ws + 16 * 1024);
  ushort_t* Wb = Xb + (size_t)M * PDIM;
  ushort_t* par = Wb + (size_t)PDIM * PDIM;

  const int n4x = (M * PDIM) / 4;  // 524288
  prep_kernel<<<1 + 2048 + (n4x + 255) / 256, 256, 0, stream>>>(
      alpha, a_mask, x, Xb, n4x, V);
  wmat_kernel<<<dim3(PDIM / 128, PDIM / 64), 256, 0, stream>>>(V, a_mask, Wb);
  gemm_kernel<<<256, 512, 0, stream>>>(Xb, Wb, par);
  combine_kernel<<<128, 512, 0, stream>>>(par, out);
}

// Round 8
// 154.893 us; speedup vs baseline: 1.0056x; 1.0056x over previous
//
#include <hip/hip_runtime.h>
#include <hip/hip_bf16.h>
#include <stdint.h>

#define PDIM 4096
#define KSEL 3687.0f
#define NITER 50

typedef unsigned short ushort_t;
typedef __attribute__((ext_vector_type(8))) __bf16 bf16x8;
typedef __attribute__((ext_vector_type(4))) float f32x4;

typedef __attribute__((address_space(3))) void lds_void;
typedef __attribute__((address_space(1))) const void glob_void;

__device__ __forceinline__ ushort_t f32_to_bf16_rne(float f) {
  union { float f; uint32_t u; } v; v.f = f;
  uint32_t r = 0x7FFFu + ((v.u >> 16) & 1u);
  return (ushort_t)((v.u + r) >> 16);
}

__device__ __forceinline__ float bf16_to_f32(ushort_t h) {
  union { uint32_t u; float f; } v; v.u = ((uint32_t)h) << 16;
  return v.f;
}

__device__ __forceinline__ void async_cp16(const void* g, void* l) {
  __builtin_amdgcn_global_load_lds((glob_void*)g, (lds_void*)l, 16, 0, 0);
}

// Raw workgroup barrier with compiler fences (rule #18).
__device__ __forceinline__ void raw_barrier() {
  __builtin_amdgcn_sched_barrier(0);
  asm volatile("" ::: "memory");
  __builtin_amdgcn_s_barrier();
  asm volatile("" ::: "memory");
  __builtin_amdgcn_sched_barrier(0);
}

// Canonical CDNA wave64 sum via DPP; result lands in lane 63.
__device__ __forceinline__ float wave_sum_dpp(float x) {
  float s = x;
  int t;
  t = __builtin_amdgcn_update_dpp(0, __float_as_int(s), 0x111, 0xF, 0xF, true);
  s += __int_as_float(t);  // row_shr:1
  t = __builtin_amdgcn_update_dpp(0, __float_as_int(s), 0x112, 0xF, 0xF, true);
  s += __int_as_float(t);  // row_shr:2
  t = __builtin_amdgcn_update_dpp(0, __float_as_int(s), 0x114, 0xF, 0xF, true);
  s += __int_as_float(t);  // row_shr:4
  t = __builtin_amdgcn_update_dpp(0, __float_as_int(s), 0x118, 0xF, 0xF, true);
  s += __int_as_float(t);  // row_shr:8
  t = __builtin_amdgcn_update_dpp(0, __float_as_int(s), 0x142, 0xA, 0xF, true);
  s += __int_as_float(t);  // row_bcast:15
  t = __builtin_amdgcn_update_dpp(0, __float_as_int(s), 0x143, 0xC, 0xF, true);
  s += __int_as_float(t);  // row_bcast:31 -> lane63 = all 64
  return s;
}

// ---------------- Kernel 1: fused Dykstra (block 0) + V->LLC prefetch
// (blocks 1..2048) + x->bf16 (blocks 2049..). R3-proven.
__global__ __launch_bounds__(256) void prep_kernel(
    const float* __restrict__ alpha, float* __restrict__ a_out,
    const float* __restrict__ x, ushort_t* __restrict__ Xb, int n4,
    const float* __restrict__ V) {
  if (blockIdx.x >= 1 && blockIdx.x <= 2048) {
    const float4* V4 = (const float4*)V;
    const int base = (blockIdx.x - 1) * 2048 + (int)threadIdx.x;
#pragma unroll
    for (int i = 0; i < 8; ++i) {
      const float4 vv = V4[base + i * 256];
      asm volatile("" :: "v"(vv.x), "v"(vv.y), "v"(vv.z), "v"(vv.w));
    }
    return;
  }
  if (blockIdx.x != 0) {
    const int i = (blockIdx.x - 2049) * 256 + threadIdx.x;
    if (i < n4) {
      const float4 v = ((const float4*)x)[i];
      ushort4 o;
      o.x = f32_to_bf16_rne(v.x);
      o.y = f32_to_bf16_rne(v.y);
      o.z = f32_to_bf16_rne(v.z);
      o.w = f32_to_bf16_rne(v.w);
      ((ushort4*)Xb)[i] = o;
    }
    return;
  }
  __shared__ float red[8];
  const int tid = threadIdx.x;
  const int lane = tid & 63;
  const int wv = tid >> 6;
  float xx[16], q[16];
  float p = 0.0f;
#pragma unroll
  for (int i = 0; i < 16; ++i) {
    xx[i] = alpha[i * 256 + tid] * 100.0f;  // s = alpha / 0.01
    q[i] = 0.0f;
  }
  for (int it = 0; it < NITER; ++it) {
    float t[16];
    float loc = 0.0f;
#pragma unroll
    for (int i = 0; i < 16; ++i) { t[i] = xx[i] + p; loc += t[i]; }
    loc = wave_sum_dpp(loc);
    const int slot = (it & 1) * 4;
    if (lane == 63) red[slot + wv] = loc;
    __syncthreads();
    const float tot = red[slot] + red[slot + 1] + red[slot + 2] + red[slot + 3];
    const float corr = (KSEL - tot) * (1.0f / 4096.0f);
    p = -corr;
#pragma unroll
    for (int i = 0; i < 16; ++i) {
      const float y = t[i] + corr;
      const float u = y + q[i];
      const float xn = fminf(fmaxf(u, 0.0f), 1.0f);
      q[i] = u - xn;
      xx[i] = xn;
    }
  }
#pragma unroll
  for (int i = 0; i < 16; ++i) a_out[i * 256 + tid] = xx[i];
}

// ---------------- Kernel 2: materialize W (row-major bf16) ----------------
// 128x64 tile, 192-row fp32 V band in LDS, pad 67. V reads LLC-hit. R3.
__global__ __launch_bounds__(256) void wmat_kernel(
    const float* __restrict__ V, const float* __restrict__ a,
    ushort_t* __restrict__ Wb) {
  __shared__ float vt[192][67];
  const int t = threadIdx.x;
  const int r0 = blockIdx.x * 128;
  const int c0 = blockIdx.y * 64;
  const int dbase = (r0 - c0 - 63 + 2 * PDIM) & (PDIM - 1);
  const int csub = (t & 15) * 4;
  const int rsub = t >> 4;
#pragma unroll
  for (int i = 0; i < 12; ++i) {
    const int ld = i * 16 + rsub;
    const int d = (dbase + ld) & (PDIM - 1);
    const float av = a[d];
    const float4 vv = *(const float4*)(V + (size_t)d * PDIM + c0 + csub);
    vt[ld][csub + 0] = av * vv.x;
    vt[ld][csub + 1] = av * vv.y;
    vt[ld][csub + 2] = av * vv.z;
    vt[ld][csub + 3] = av * vv.w;
  }
  __syncthreads();
#pragma unroll
  for (int k = 0; k < 4; ++k) {
    const int ry = (t >> 3) + k * 32;
    const int cb = (t & 7) * 8;
    ushort_t pk[8];
#pragma unroll
    for (int j = 0; j < 8; ++j) {
      const int c = cb + j;
      pk[j] = f32_to_bf16_rne(vt[ry - c + 63][c]);
    }
    *(uint4*)(Wb + (size_t)(r0 + ry) * PDIM + c0 + cb) = *(const uint4*)pk;
  }
}

// ---------------- Kernel 3: bf16 MFMA GEMM, BM=BN=256, BK=64, z=8 --------
// R8: counted-vmcnt 4-phase pipeline (true T3+T4). Phase q computes one
// C-quadrant (mh,nh): 12 ds_read_b128 + 16 MFMA. Stage granularity = the
// matching half-tiles; parity-scheduled stage order + reversed phase order
// on odd tiles stagger first-needs so a UNIFORM vmcnt(4) per phase
// certifies exactly the next phase's data. vmcnt(0) only in the prologue;
// final tile drains 2 -> 0. Buffer-reuse edges closed by the post-MFMA
// barrier (stage of t+1 issued only after all waves finished reading the
// target buffer in t-1).
__global__ __launch_bounds__(512, 2) void gemm_kernel(
    const ushort_t* __restrict__ Xb, const ushort_t* __restrict__ Wb,
    ushort_t* __restrict__ par) {
  constexpr int Kdim = 4096, KQ = 512, NIT = KQ / 64;
  __shared__ __align__(16) ushort_t As[2][256 * 64];
  __shared__ __align__(16) ushort_t Bs[2][256 * 64];
  const int tid = threadIdx.x;
  const int lane = tid & 63;
  const int w = tid >> 6;        // 0..7
  const int l15 = lane & 15;
  const int quad = lane >> 4;
  const int wr = w >> 2;         // 0..1 (M half)
  const int wc = w & 3;          // 0..3 (N quarter)
  const int bid = blockIdx.x;    // 0..255
  const int u = (bid & 7) * 32 + (bid >> 3);  // XCD decode (R7-proven)
  const int z = u & 7;
  const int tile = u >> 3;       // 0..31
  const int mblk = tile & 1;
  const int nblk = tile >> 1;    // 0..15
  const int m0 = mblk * 256;
  const int n0 = nblk * 256;
  const int kbase = z * KQ;
  const int crow8 = lane >> 3;   // 0..7
  const int slotj = lane & 7;

  f32x4 acc[8][4];
#pragma unroll
  for (int mt = 0; mt < 8; ++mt)
#pragma unroll
    for (int nt = 0; nt < 4; ++nt) acc[mt][nt] = (f32x4){0.f, 0.f, 0.f, 0.f};

  // A-half h (read by phase mh=h): chunks {8h+w, 16+8h+w}
  auto stageA = [&](int buf, int it, int h) {
    const int k0 = kbase + it * 64;
#pragma unroll
    for (int L = 0; L < 2; ++L) {
      const int chunk = L * 16 + h * 8 + w;
      const int row = chunk * 8 + crow8;
      const int j = slotj ^ (row & 7);
      async_cp16(Xb + (size_t)(m0 + row) * Kdim + k0 + j * 8,
                 (char*)&As[buf][0] + (size_t)chunk * 1024);
    }
  };
  // B-half h (read by phase nh=h): chunks {g*8 + h*4 + c}
  auto stageB = [&](int buf, int it, int h) {
    const int k0 = kbase + it * 64;
#pragma unroll
    for (int L = 0; L < 2; ++L) {
      const int idx = L * 8 + w;
      const int chunk = (idx >> 2) * 8 + h * 4 + (idx & 3);
      const int row = chunk * 8 + crow8;
      const int j = slotj ^ (row & 7);
      async_cp16(Wb + (size_t)(n0 + row) * Kdim + k0 + j * 8,
                 (char*)&Bs[buf][0] + (size_t)chunk * 1024);
    }
  };
  // unit code: 0=A0 1=A1 2=B0 3=B1
  auto stage_unit = [&](int buf, int it, int u4) {
    if (u4 < 2) stageA(buf, it, u4);
    else stageB(buf, it, u4 - 2);
  };

  // Prologue: tile 0 in the order of its first-needs (A0,B0,B1,A1).
  stage_unit(0, 0, 0);
  stage_unit(0, 0, 2);
  stage_unit(0, 0, 3);
  stage_unit(0, 0, 1);
  asm volatile("s_waitcnt vmcnt(0)" ::: "memory");
  raw_barrier();

  for (int t = 0; t < NIT; ++t) {
    const int cur = t & 1;
    const ushort_t* __restrict__ Ab = &As[cur][0];
    const ushort_t* __restrict__ Bb = &Bs[cur][0];
#pragma unroll
    for (int q = 0; q < 4; ++q) {
      // quadrant for this phase (reversed order on odd tiles)
      const int qq = (t & 1) ? (3 - q) : q;
      const int mh = qq >> 1;
      const int nh = qq & 1;
      // ds_read this quadrant's fragments (certified by prev phase)
      bf16x8 afr[4][2];
      bf16x8 bfr[2][2];
#pragma unroll
      for (int mi = 0; mi < 4; ++mi)
#pragma unroll
        for (int k2 = 0; k2 < 2; ++k2) {
          const int row = wr * 128 + (mh * 4 + mi) * 16 + l15;
          const int cj = k2 * 4 + quad;
          afr[mi][k2] = *(const bf16x8*)&Ab[(row * 8 + (cj ^ (row & 7))) * 8];
        }
#pragma unroll
      for (int ni = 0; ni < 2; ++ni)
#pragma unroll
        for (int k2 = 0; k2 < 2; ++k2) {
          const int row = wc * 64 + (nh * 2 + ni) * 16 + l15;
          const int cj = k2 * 4 + quad;
          bfr[ni][k2] = *(const bf16x8*)&Bb[(row * 8 + (cj ^ (row & 7))) * 8];
        }
      // stage one half-unit of tile t+1 (order matches t+1's first-needs)
      if (t + 1 < NIT) {
        // even t (staging for odd): A1,B1,B0,A0 ; odd t: A0,B0,B1,A1
        const int evst[4] = {1, 3, 2, 0};
        const int odst[4] = {0, 2, 3, 1};
        stage_unit(cur ^ 1, t + 1, (t & 1) ? odst[q] : evst[q]);
      }
      raw_barrier();
      // Counted wait: certify the halves the NEXT phase reads.
      if (t == NIT - 1) {
        if (q == 0) asm volatile("s_waitcnt vmcnt(2)" ::: "memory");
        else if (q == 1) asm volatile("s_waitcnt vmcnt(0)" ::: "memory");
      } else {
        asm volatile("s_waitcnt vmcnt(4)" ::: "memory");
      }
      asm volatile("s_waitcnt lgkmcnt(0)" ::: "memory");
      __builtin_amdgcn_sched_barrier(0);  // rule #18
      __builtin_amdgcn_s_setprio(1);
#pragma unroll
      for (int mi = 0; mi < 4; ++mi)
#pragma unroll
        for (int ni = 0; ni < 2; ++ni) {
          acc[mh * 4 + mi][nh * 2 + ni] =
              __builtin_amdgcn_mfma_f32_16x16x32_bf16(
                  afr[mi][0], bfr[ni][0], acc[mh * 4 + mi][nh * 2 + ni],
                  0, 0, 0);
          acc[mh * 4 + mi][nh * 2 + ni] =
              __builtin_amdgcn_mfma_f32_16x16x32_bf16(
                  afr[mi][1], bfr[ni][1], acc[mh * 4 + mi][nh * 2 + ni],
                  0, 0, 0);
        }
      __builtin_amdgcn_s_setprio(0);
      raw_barrier();
    }
  }
  // epilogue: bf16 partials, blocked order, 8B/lane coalesced. (R6-proven)
  ushort_t* pbase = par + ((size_t)z * 32 + tile) * 65536;
#pragma unroll
  for (int mt = 0; mt < 8; ++mt) {
#pragma unroll
    for (int nt = 0; nt < 4; ++nt) {
      const int slot = mt * 4 + nt;
      ushort4 o;
      o.x = f32_to_bf16_rne(acc[mt][nt][0]);
      o.y = f32_to_bf16_rne(acc[mt][nt][1]);
      o.z = f32_to_bf16_rne(acc[mt][nt][2]);
      o.w = f32_to_bf16_rne(acc[mt][nt][3]);
      *(ushort4*)(pbase + (size_t)(slot * 512 + tid) * 4) = o;
    }
  }
}

// ---------------- Kernel 4: sum 8 blocked bf16 partials -> row-major out --
// Grid = 32 tiles x 4 quarters (128 blocks x 512 thr). R6-proven.
__global__ __launch_bounds__(512) void combine_kernel(
    const ushort_t* __restrict__ par, float* __restrict__ out) {
  const int tile = blockIdx.x >> 2;  // 0..31
  const int qh = blockIdx.x & 3;
  const int mblk = tile & 1;
  const int nblk = tile >> 1;
  const int m0 = mblk * 256;
  const int n0 = nblk * 256;
  const int tid = threadIdx.x;
  const int lane = tid & 63;
  const int w = tid >> 6;
  const int wr = w >> 2;
  const int wc = w & 3;
  const int l15 = lane & 15;
  const int quad = lane >> 4;
#pragma unroll
  for (int ss = 0; ss < 8; ++ss) {
    const int slot = qh * 8 + ss;  // 0..31
    float s0 = 0.f, s1 = 0.f, s2 = 0.f, s3 = 0.f;
#pragma unroll
    for (int z = 0; z < 8; ++z) {
      const ushort4 v = *(const ushort4*)(par +
          ((size_t)z * 32 + tile) * 65536 + (size_t)(slot * 512 + tid) * 4);
      s0 += bf16_to_f32(v.x);
      s1 += bf16_to_f32(v.y);
      s2 += bf16_to_f32(v.z);
      s3 += bf16_to_f32(v.w);
    }
    const int mt = slot >> 2;
    const int nt = slot & 3;
    const int mb = m0 + wr * 128 + mt * 16 + quad * 4;
    const int n = n0 + wc * 64 + nt * 16 + l15;
    out[(size_t)(mb + 0) * PDIM + n] = s0;
    out[(size_t)(mb + 1) * PDIM + n] = s1;
    out[(size_t)(mb + 2) * PDIM + n] = s2;
    out[(size_t)(mb + 3) * PDIM + n] = s3;
  }
}

extern "C" void kernel_launch(void* const* d_in, const int* in_sizes, int n_in,
                              void* d_out, int out_size, void* d_ws,
                              size_t ws_size, hipStream_t stream) {
  const float* x = (const float*)d_in[0];
  const float* V = (const float*)d_in[1];
  const float* alpha = (const float*)d_in[2];
  float* out = (float*)d_out;
  const int M = in_sizes[0] / PDIM;  // 512

  // ws: a(16KB) | Xb bf16 (4MB) | Wb bf16 (32MB) | partials bf16 8x4MB
  float* a_mask = (float*)d_ws;
  ushort_t* Xb = (ushort_t*)((char*)d_ws + 16 * 1024);
  ushort_t* Wb = Xb + (size_t)M * PDIM;
  ushort_t* par = Wb + (size_t)PDIM * PDIM;

  const int n4x = (M * PDIM) / 4;  // 524288
  prep_kernel<<<1 + 2048 + (n4x + 255) / 256, 256, 0, stream>>>(
      alpha, a_mask, x, Xb, n4x, V);
  wmat_kernel<<<dim3(PDIM / 128, PDIM / 64), 256, 0, stream>>>(V, a_mask, Wb);
  gemm_kernel<<<256, 512, 0, stream>>>(Xb, Wb, par);
  combine_kernel<<<128, 512, 0, stream>>>(par, out);
}

// Round 9
// 148.634 us; speedup vs baseline: 1.0479x; 1.0421x over previous
//
#include <hip/hip_runtime.h>
#include <hip/hip_bf16.h>
#include <stdint.h>

#define PDIM 4096
#define KSEL 3687.0f
#define NITER 50

typedef unsigned short ushort_t;
typedef __attribute__((ext_vector_type(8))) __bf16 bf16x8;
typedef __attribute__((ext_vector_type(4))) float f32x4;

typedef __attribute__((address_space(3))) void lds_void;
typedef __attribute__((address_space(1))) const void glob_void;

__device__ __forceinline__ ushort_t f32_to_bf16_rne(float f) {
  union { float f; uint32_t u; } v; v.f = f;
  uint32_t r = 0x7FFFu + ((v.u >> 16) & 1u);
  return (ushort_t)((v.u + r) >> 16);
}

__device__ __forceinline__ float bf16_to_f32(ushort_t h) {
  union { uint32_t u; float f; } v; v.u = ((uint32_t)h) << 16;
  return v.f;
}

__device__ __forceinline__ void async_cp16(const void* g, void* l) {
  __builtin_amdgcn_global_load_lds((glob_void*)g, (lds_void*)l, 16, 0, 0);
}

// Canonical CDNA wave64 sum via DPP (row_shr 1/2/4/8 + row_bcast 15/31).
// Result lands in lane 63.
__device__ __forceinline__ float wave_sum_dpp(float x) {
  float s = x;
  int t;
  t = __builtin_amdgcn_update_dpp(0, __float_as_int(s), 0x111, 0xF, 0xF, true);
  s += __int_as_float(t);  // row_shr:1
  t = __builtin_amdgcn_update_dpp(0, __float_as_int(s), 0x112, 0xF, 0xF, true);
  s += __int_as_float(t);  // row_shr:2
  t = __builtin_amdgcn_update_dpp(0, __float_as_int(s), 0x114, 0xF, 0xF, true);
  s += __int_as_float(t);  // row_shr:4
  t = __builtin_amdgcn_update_dpp(0, __float_as_int(s), 0x118, 0xF, 0xF, true);
  s += __int_as_float(t);  // row_shr:8 -> lane15/31/47/63 hold row sums
  t = __builtin_amdgcn_update_dpp(0, __float_as_int(s), 0x142, 0xA, 0xF, true);
  s += __int_as_float(t);  // row_bcast:15 -> lane31 = rows0+1, lane63 = rows2+3
  t = __builtin_amdgcn_update_dpp(0, __float_as_int(s), 0x143, 0xC, 0xF, true);
  s += __int_as_float(t);  // row_bcast:31 -> lane63 = all 64
  return s;
}

// ---------------- Kernel 1: fused Dykstra (block 0) + V->LLC prefetch
// (blocks 1..2048) + x->bf16 (blocks 2049..). The V prefetch streams 64 MiB
// into Infinity Cache under the ~13us serial-Dykstra shadow so wmat's read
// side becomes LLC-resident instead of HBM-bound.
__global__ __launch_bounds__(256) void prep_kernel(
    const float* __restrict__ alpha, float* __restrict__ a_out,
    const float* __restrict__ x, ushort_t* __restrict__ Xb, int n4,
    const float* __restrict__ V) {
  if (blockIdx.x >= 1 && blockIdx.x <= 2048) {
    // V prefetch: 2048 blocks x 256 threads x 8 float4 = 64 MiB.
    const float4* V4 = (const float4*)V;
    const int base = (blockIdx.x - 1) * 2048 + (int)threadIdx.x;
#pragma unroll
    for (int i = 0; i < 8; ++i) {
      const float4 vv = V4[base + i * 256];
      // keep-alive: prevent DCE of the fill-only loads (guide rule #17)
      asm volatile("" :: "v"(vv.x), "v"(vv.y), "v"(vv.z), "v"(vv.w));
    }
    return;
  }
  if (blockIdx.x != 0) {
    const int i = (blockIdx.x - 2049) * 256 + threadIdx.x;
    if (i < n4) {
      const float4 v = ((const float4*)x)[i];
      ushort4 o;
      o.x = f32_to_bf16_rne(v.x);
      o.y = f32_to_bf16_rne(v.y);
      o.z = f32_to_bf16_rne(v.z);
      o.w = f32_to_bf16_rne(v.w);
      ((ushort4*)Xb)[i] = o;
    }
    return;
  }
  __shared__ float red[8];
  const int tid = threadIdx.x;
  const int lane = tid & 63;
  const int wv = tid >> 6;
  float xx[16], q[16];
  float p = 0.0f;
#pragma unroll
  for (int i = 0; i < 16; ++i) {
    xx[i] = alpha[i * 256 + tid] * 100.0f;  // s = alpha / 0.01
    q[i] = 0.0f;
  }
  for (int it = 0; it < NITER; ++it) {
    float t[16];
    float loc = 0.0f;
#pragma unroll
    for (int i = 0; i < 16; ++i) { t[i] = xx[i] + p; loc += t[i]; }
    loc = wave_sum_dpp(loc);
    const int slot = (it & 1) * 4;
    if (lane == 63) red[slot + wv] = loc;
    __syncthreads();
    const float tot = red[slot] + red[slot + 1] + red[slot + 2] + red[slot + 3];
    const float corr = (KSEL - tot) * (1.0f / 4096.0f);
    p = -corr;
#pragma unroll
    for (int i = 0; i < 16; ++i) {
      const float y = t[i] + corr;
      const float u = y + q[i];
      const float xn = fminf(fmaxf(u, 0.0f), 1.0f);
      q[i] = u - xn;
      xx[i] = xn;
    }
  }
#pragma unroll
  for (int i = 0; i < 16; ++i) a_out[i * 256 + tid] = xx[i];
}

// ---------------- Kernel 2: materialize W (row-major bf16) ----------------
// R3-proven config: 128x64 tile, 192-row fp32 V band in LDS, pad 67,
// phase-2 stores 128B-per-row segments. V reads LLC-hit (prep prefetch).
__global__ __launch_bounds__(256) void wmat_kernel(
    const float* __restrict__ V, const float* __restrict__ a,
    ushort_t* __restrict__ Wb) {
  __shared__ float vt[192][67];
  const int t = threadIdx.x;
  const int r0 = blockIdx.x * 128;
  const int c0 = blockIdx.y * 64;
  const int dbase = (r0 - c0 - 63 + 2 * PDIM) & (PDIM - 1);
  const int csub = (t & 15) * 4;
  const int rsub = t >> 4;
#pragma unroll
  for (int i = 0; i < 12; ++i) {
    const int ld = i * 16 + rsub;
    const int d = (dbase + ld) & (PDIM - 1);
    const float av = a[d];
    const float4 vv = *(const float4*)(V + (size_t)d * PDIM + c0 + csub);
    vt[ld][csub + 0] = av * vv.x;
    vt[ld][csub + 1] = av * vv.y;
    vt[ld][csub + 2] = av * vv.z;
    vt[ld][csub + 3] = av * vv.w;
  }
  __syncthreads();
#pragma unroll
  for (int k = 0; k < 4; ++k) {
    const int ry = (t >> 3) + k * 32;
    const int cb = (t & 7) * 8;
    ushort_t pk[8];
#pragma unroll
    for (int j = 0; j < 8; ++j) {
      const int c = cb + j;
      pk[j] = f32_to_bf16_rne(vt[ry - c + 63][c]);
    }
    *(uint4*)(Wb + (size_t)(r0 + ry) * PDIM + c0 + cb) = *(const uint4*)pk;
  }
}

// ---------------- Kernel 3: bf16 MFMA GEMM, split-K x4, BM=BN=128 --------
// Measured-best structure (R1, 148.96us): 2-barrier loop, 2 blocks/CU
// co-residency provides the stage/compute overlap (m114 mechanism).
// Bracketing experiments R5-R8 (dbuf+counted vmcnt, 256^2, 4-phase
// drain0/counted) all <= this at NIT=8, L2-resident regime.
__global__ __launch_bounds__(256, 3) void gemm_kernel(
    const ushort_t* __restrict__ Xb, const ushort_t* __restrict__ Wb,
    ushort_t* __restrict__ par) {
  constexpr int Kdim = 4096, KQ = 1024;
  __shared__ __align__(16) ushort_t As[128 * 64];
  __shared__ __align__(16) ushort_t Bs[128 * 64];
  const int tid = threadIdx.x;
  const int lane = tid & 63;
  const int w = tid >> 6;
  const int l15 = lane & 15;
  const int quad = lane >> 4;
  const int z = blockIdx.x;     // 0..3
  const int nblk = blockIdx.y;  // 0..31
  const int mblk = blockIdx.z;  // 0..3
  const int m0 = mblk * 128;
  const int n0 = nblk * 128;
  const int kbase = z * KQ;
  const int arow = lane >> 3;
  const int aslot = lane & 7;

  f32x4 acc[8][2];
#pragma unroll
  for (int mt = 0; mt < 8; ++mt)
#pragma unroll
    for (int nt = 0; nt < 2; ++nt) acc[mt][nt] = (f32x4){0.f, 0.f, 0.f, 0.f};

  for (int it = 0; it < KQ / 64; ++it) {
    const int k0 = kbase + it * 64;
#pragma unroll
    for (int s = w; s < 16; s += 4) {
      const int row = s * 8 + arow;
      const int j = aslot ^ (row & 7);
      async_cp16(Xb + (size_t)(m0 + row) * Kdim + k0 + j * 8,
                 (char*)As + (size_t)s * 1024);
      async_cp16(Wb + (size_t)(n0 + row) * Kdim + k0 + j * 8,
                 (char*)Bs + (size_t)s * 1024);
    }
    __syncthreads();
#pragma unroll
    for (int kk = 0; kk < 64; kk += 32) {
      const int cj = (kk >> 3) + quad;
      bf16x8 bfv[2];
#pragma unroll
      for (int nt = 0; nt < 2; ++nt) {
        const int row = w * 32 + nt * 16 + l15;
        bfv[nt] = *(const bf16x8*)&Bs[(row * 8 + (cj ^ (row & 7))) * 8];
      }
#pragma unroll
      for (int mt = 0; mt < 8; ++mt) {
        const int row = mt * 16 + l15;
        const bf16x8 af = *(const bf16x8*)&As[(row * 8 + (cj ^ (row & 7))) * 8];
        acc[mt][0] = __builtin_amdgcn_mfma_f32_16x16x32_bf16(af, bfv[0],
                                                             acc[mt][0], 0, 0, 0);
        acc[mt][1] = __builtin_amdgcn_mfma_f32_16x16x32_bf16(af, bfv[1],
                                                             acc[mt][1], 0, 0, 0);
      }
    }
    __syncthreads();
  }
  // epilogue: bf16 partials in blocked order, 8B/lane coalesced.
  const int tile = nblk * 4 + mblk;  // 0..127
  ushort_t* pbase = par + ((size_t)z * 128 + tile) * 16384;
#pragma unroll
  for (int mt = 0; mt < 8; ++mt) {
#pragma unroll
    for (int nt = 0; nt < 2; ++nt) {
      const int slot = mt * 2 + nt;
      ushort4 o;
      o.x = f32_to_bf16_rne(acc[mt][nt][0]);
      o.y = f32_to_bf16_rne(acc[mt][nt][1]);
      o.z = f32_to_bf16_rne(acc[mt][nt][2]);
      o.w = f32_to_bf16_rne(acc[mt][nt][3]);
      *(ushort4*)(pbase + (size_t)(slot * 256 + tid) * 4) = o;
    }
  }
}

// ---------------- Kernel 4: sum 4 blocked bf16 partials -> row-major out --
// Grid = 128 tiles x 4 quarters (512 blocks, 2/CU); mirrors gemm geometry.
__global__ __launch_bounds__(256) void combine_kernel(
    const ushort_t* __restrict__ par, float* __restrict__ out) {
  const int tile = blockIdx.x >> 2;  // 0..127
  const int qh = blockIdx.x & 3;
  const int nblk = tile >> 2;
  const int mblk = tile & 3;
  const int m0 = mblk * 128;
  const int n0 = nblk * 128;
  const int tid = threadIdx.x;
  const int lane = tid & 63;
  const int w = tid >> 6;
  const int l15 = lane & 15;
  const int quad = lane >> 4;
#pragma unroll
  for (int ss = 0; ss < 4; ++ss) {
    const int slot = qh * 4 + ss;
    float s0 = 0.f, s1 = 0.f, s2 = 0.f, s3 = 0.f;
#pragma unroll
    for (int z = 0; z < 4; ++z) {
      const ushort4 v = *(const ushort4*)(par +
          ((size_t)z * 128 + tile) * 16384 + (size_t)(slot * 256 + tid) * 4);
      s0 += bf16_to_f32(v.x);
      s1 += bf16_to_f32(v.y);
      s2 += bf16_to_f32(v.z);
      s3 += bf16_to_f32(v.w);
    }
    const int mt = slot >> 1;
    const int nt = slot & 1;
    const int mb = m0 + mt * 16 + quad * 4;
    const int n = n0 + w * 32 + nt * 16 + l15;
    out[(size_t)(mb + 0) * PDIM + n] = s0;
    out[(size_t)(mb + 1) * PDIM + n] = s1;
    out[(size_t)(mb + 2) * PDIM + n] = s2;
    out[(size_t)(mb + 3) * PDIM + n] = s3;
  }
}

extern "C" void kernel_launch(void* const* d_in, const int* in_sizes, int n_in,
                              void* d_out, int out_size, void* d_ws,
                              size_t ws_size, hipStream_t stream) {
  const float* x = (const float*)d_in[0];
  const float* V = (const float*)d_in[1];
  const float* alpha = (const float*)d_in[2];
  float* out = (float*)d_out;
  const int M = in_sizes[0] / PDIM;  // 512

  // ws: a(16KB) | Xb bf16 (4MB) | Wb bf16 (32MB) | partials bf16 4x4MB
  float* a_mask = (float*)d_ws;
  ushort_t* Xb = (ushort_t*)((char*)d_ws + 16 * 1024);
  ushort_t* Wb = Xb + (size_t)M * PDIM;
  ushort_t* par = Wb + (size_t)PDIM * PDIM;

  const int n4x = (M * PDIM) / 4;  // 524288
  // grid: [0] Dykstra | [1..2048] V->LLC prefetch | [2049..] x->bf16
  prep_kernel<<<1 + 2048 + (n4x + 255) / 256, 256, 0, stream>>>(
      alpha, a_mask, x, Xb, n4x, V);
  wmat_kernel<<<dim3(PDIM / 128, PDIM / 64), 256, 0, stream>>>(V, a_mask, Wb);
  gemm_kernel<<<dim3(4, PDIM / 128, M / 128), 256, 0, stream>>>(Xb, Wb, par);
  combine_kernel<<<512, 256, 0, stream>>>(par, out);
}